// Round 16
// baseline (1299.787 us; speedup 1.0000x reference)
//
#include <hip/hip_runtime.h>
#include <hip/hip_bf16.h>
#include <math.h>

// ---------------- constants ----------------
#define BATCH 16
#define CIN 3
#define SIMG 512
#define PPATCH 16
#define DMODEL 256
#define HIDDEN 1024
#define LAYERS 8
#define NHEADS 4
#define DHEAD 64
#define NTOK 1025            // 1024 patches + cls
#define NROWS (BATCH * NTOK) // 16400
#define NCLS 1000
#define VSTR 1032            // padded token stride for vT (16B-aligned rows)

typedef __attribute__((ext_vector_type(8))) short bf16x8;
typedef __attribute__((ext_vector_type(4))) float f32x4;

#define MFMA16(a, b, c) __builtin_amdgcn_mfma_f32_16x16x32_bf16(a, b, c, 0, 0, 0)

__device__ __forceinline__ ushort f2bf(float f) {
    union { float f; unsigned u; } v; v.f = f;
    unsigned r = v.u + 0x7fff + ((v.u >> 16) & 1);
    return (ushort)(r >> 16);
}
__device__ __forceinline__ float bf2f(ushort u) {
    union { unsigned u; float f; } v; v.u = ((unsigned)u) << 16;
    return v.f;
}
__device__ __forceinline__ unsigned pk2(ushort a, ushort b) {
    return (unsigned)a | ((unsigned)b << 16);
}
// byte offset into a [rows][64]-bf16 LDS tile (128B rows), XOR-swizzled
__device__ __forceinline__ int swz16(int row, int bcol) {
    return row * 128 + (bcol ^ ((row & 7) << 4));
}
// async global->LDS, 16B per lane. LDS dest = wave-uniform base + lane*16.
__device__ __forceinline__ void gload16(const void* g, void* l) {
    __builtin_amdgcn_global_load_lds(
        (const __attribute__((address_space(1))) unsigned int*)g,
        (__attribute__((address_space(3))) unsigned int*)l,
        16, 0, 0);
}

// ---------------- RoPE tables ----------------
__global__ void rope_tab_kernel(float* __restrict__ cosb, float* __restrict__ sinb) {
    int i = blockIdx.x * 256 + threadIdx.x;
    if (i >= NTOK * 128) return;
    int n = i >> 7, j = i & 127;
    float inv = powf(10000.0f, -(float)(2 * j) / 256.0f);
    float ang = (float)n * inv;
    cosb[i] = cosf(ang);
    sinb[i] = sinf(ang);
}

// ---------------- cls token broadcast ----------------
__global__ void cls_kernel(const float* __restrict__ cls, float* __restrict__ tok) {
    int i = blockIdx.x * 256 + threadIdx.x;
    int b = i >> 8, d = i & 255;
    tok[(size_t)b * NTOK * DMODEL + d] = cls[d];
}

// ---------------- bf16 convert (conv weight, already [N][K]) ----------------
__global__ void cvt_bf16_kernel(const float* __restrict__ in, ushort* __restrict__ out, int n) {
    int base = (blockIdx.x * 256 + threadIdx.x) * 4;
    if (base >= n) return;
    float4 v = *(const float4*)(in + base);
    *(ushort4*)(out + base) = make_ushort4(f2bf(v.x), f2bf(v.y), f2bf(v.z), f2bf(v.w));
}

// ---------------- weight transpose + bf16 convert: WT[n][k] = bf16(W[k][n]) ----------------
__global__ __launch_bounds__(256) void transpose_cvt_kernel(
    const float* __restrict__ W, ushort* __restrict__ WT, int K, int N,
    long wl, long wtl)
{
    __shared__ float t[32][33];
    int l = blockIdx.z;
    W  += (size_t)l * wl;
    WT += (size_t)l * wtl;
    int kb = blockIdx.y * 32, nb = blockIdx.x * 32;
    int tx = threadIdx.x & 31, ty = threadIdx.x >> 5;
    #pragma unroll
    for (int i = 0; i < 32; i += 8)
        t[ty + i][tx] = W[(size_t)(kb + ty + i) * N + nb + tx];
    __syncthreads();
    #pragma unroll
    for (int i = 0; i < 32; i += 8)
        WT[(size_t)(nb + ty + i) * K + kb + tx] = f2bf(t[tx][ty + i]);
}

// ---------------- layernorm (used once, for layer-0 LN1) ----------------
__global__ __launch_bounds__(256) void ln_kernel(
    const float* __restrict__ in, ushort* __restrict__ outp,
    const float* __restrict__ g, const float* __restrict__ bta, int nrows)
{
    int row = blockIdx.x * 4 + (threadIdx.x >> 6);
    int lane = threadIdx.x & 63;
    if (row >= nrows) return;
    const float* xr = in + (size_t)row * DMODEL;
    float4 v = *(const float4*)(xr + lane * 4);
    float s = v.x + v.y + v.z + v.w;
    float ss = v.x * v.x + v.y * v.y + v.z * v.z + v.w * v.w;
    #pragma unroll
    for (int m = 1; m < 64; m <<= 1) {
        s += __shfl_xor(s, m, 64);
        ss += __shfl_xor(ss, m, 64);
    }
    float mean = s * (1.0f / 256.0f);
    float var = ss * (1.0f / 256.0f) - mean * mean;
    float inv = rsqrtf(var + 1e-5f);
    float4 gv = *(const float4*)(g + lane * 4);
    float4 bv = *(const float4*)(bta + lane * 4);
    ushort4 o = make_ushort4(f2bf((v.x - mean) * inv * gv.x + bv.x),
                             f2bf((v.y - mean) * inv * gv.y + bv.y),
                             f2bf((v.z - mean) * inv * gv.z + bv.z),
                             f2bf((v.w - mean) * inv * gv.w + bv.w));
    *(ushort4*)(outp + (size_t)row * DMODEL + lane * 4) = o;
}

// ---------------- patch embed as MFMA GEMM (fused im2col, XCD-swizzled) ----------------
__global__ __launch_bounds__(256) void patch_gemm(
    const float* __restrict__ x, const ushort* __restrict__ Wb,
    const float* __restrict__ bias, float* __restrict__ h)
{
    __shared__ __align__(16) ushort As[128 * 64];
    __shared__ __align__(16) ushort Bs[64 * 64];
    int bid = blockIdx.x;
    int xcd = bid & 7, idx = bid >> 3;          // idx 0..63
    int m0 = (xcd * 16 + (idx >> 2)) * 128;     // m-tile 0..127
    int n0 = (idx & 3) * 64;
    int tid = threadIdx.x;
    int w = tid >> 6, l = tid & 63;
    int lr = l & 15, lg = l >> 4;
    int wm = w & 1, wn = w >> 1;
    f32x4 acc[4][2] = {};

    for (int k0 = 0; k0 < 768; k0 += 64) {
        __syncthreads();
        #pragma unroll
        for (int i = 0; i < 4; ++i) {
            int id = tid + 256 * i; int r = id >> 3, c8 = id & 7;
            int m = m0 + r;
            int b_ = m >> 10, pi = m & 1023, ph = pi >> 5, pw = pi & 31;
            int k = k0 + c8 * 8;
            int c = k >> 8, rem = k & 255, pr = rem >> 4, q = rem & 15;
            const float* src = x + ((size_t)((b_ * 3 + c) * SIMG) + ph * 16 + pr) * SIMG
                                 + pw * 16 + q;
            float4 v0 = *(const float4*)src;
            float4 v1 = *(const float4*)(src + 4);
            uint4 t;
            t.x = pk2(f2bf(v0.x), f2bf(v0.y));
            t.y = pk2(f2bf(v0.z), f2bf(v0.w));
            t.z = pk2(f2bf(v1.x), f2bf(v1.y));
            t.w = pk2(f2bf(v1.z), f2bf(v1.w));
            *(uint4*)((char*)As + swz16(r, c8 * 16)) = t;
        }
        #pragma unroll
        for (int i = 0; i < 2; ++i) {
            int id = tid + 256 * i; int r = id >> 3, c8 = id & 7;
            uint4 t = *(const uint4*)(Wb + (size_t)(n0 + r) * 768 + k0 + c8 * 8);
            *(uint4*)((char*)Bs + swz16(r, c8 * 16)) = t;
        }
        __syncthreads();
        #pragma unroll
        for (int ks = 0; ks < 2; ++ks) {
            bf16x8 af[4];
            #pragma unroll
            for (int mf = 0; mf < 4; ++mf)
                af[mf] = *(const bf16x8*)((char*)As + swz16(wm * 64 + mf * 16 + lr, ks * 64 + lg * 16));
            #pragma unroll
            for (int nf = 0; nf < 2; ++nf) {
                bf16x8 bfr = *(const bf16x8*)((char*)Bs + swz16(wn * 32 + nf * 16 + lr, ks * 64 + lg * 16));
                #pragma unroll
                for (int mf = 0; mf < 4; ++mf)
                    acc[mf][nf] = MFMA16(af[mf], bfr, acc[mf][nf]);
            }
        }
    }
    #pragma unroll
    for (int mf = 0; mf < 4; ++mf) {
        #pragma unroll
        for (int nf = 0; nf < 2; ++nf) {
            int n = n0 + wn * 32 + nf * 16 + lr;
            float bb = bias[n];
            #pragma unroll
            for (int e = 0; e < 4; ++e) {
                int m = m0 + wm * 64 + mf * 16 + lg * 4 + e;
                int b_ = m >> 10, pi = m & 1023;
                h[((size_t)(b_ * NTOK + 1 + pi)) * DMODEL + n] = acc[mf][nf][e] + bb;
            }
        }
    }
}

// ---------------- fused QKV MFMA GEMM (128x128 tile, 512 threads / 8 waves, XCD-swizzled) ----------------
__global__ __launch_bounds__(512) void gemm_qkv(
    const ushort* __restrict__ A, const ushort* __restrict__ WT,
    const float* __restrict__ bq, const float* __restrict__ bk,
    const float* __restrict__ bv,
    ushort* __restrict__ qbf, ushort* __restrict__ kbf, ushort* __restrict__ vT,
    const float* __restrict__ cosb, const float* __restrict__ sinb, int M)
{
    __shared__ __align__(16) ushort As[128 * 64];
    __shared__ __align__(16) ushort Bs[128 * 64];
    int bid = blockIdx.x;
    int xcd = bid & 7, idx = bid >> 3;          // idx 0..101
    int mt = xcd * 17 + idx / 6;                // 0..135 (>=129 dead)
    int m0 = mt * 128;
    if (m0 >= M) return;
    int n0 = (idx % 6) * 128;
    int tid = threadIdx.x;                      // 0..511
    int w = tid >> 6, l = tid & 63;
    int lr = l & 15, lg = l >> 4;
    int wm = w & 1, wn = w >> 1;                // 2m x 4n waves; wave = 64 x 32
    int wb0 = (tid & ~63) * 16;
    f32x4 acc[4][2] = {};

    for (int k0 = 0; k0 < 256; k0 += 64) {
        __syncthreads();
        #pragma unroll
        for (int i = 0; i < 2; ++i) {
            int id = tid + 512 * i; int r = id >> 3, c8 = id & 7;
            int mrow = m0 + r; if (mrow > M - 1) mrow = M - 1;
            int c8s = c8 ^ (r & 7);
            gload16(A + (size_t)mrow * 256 + k0 + c8s * 8, (char*)As + wb0 + i * 8192);
        }
        #pragma unroll
        for (int i = 0; i < 2; ++i) {
            int id = tid + 512 * i; int r = id >> 3, c8 = id & 7;
            int c8s = c8 ^ (r & 7);
            gload16(WT + (size_t)(n0 + r) * 256 + k0 + c8s * 8, (char*)Bs + wb0 + i * 8192);
        }
        __syncthreads();
        #pragma unroll
        for (int ks = 0; ks < 2; ++ks) {
            bf16x8 af[4], bf[2];
            #pragma unroll
            for (int mf = 0; mf < 4; ++mf)
                af[mf] = *(const bf16x8*)((char*)As + swz16(wm * 64 + mf * 16 + lr, ks * 64 + lg * 16));
            #pragma unroll
            for (int nf = 0; nf < 2; ++nf)
                bf[nf] = *(const bf16x8*)((char*)Bs + swz16(wn * 32 + nf * 16 + lr, ks * 64 + lg * 16));
            #pragma unroll
            for (int nf = 0; nf < 2; ++nf)
                #pragma unroll
                for (int mf = 0; mf < 4; ++mf)
                    acc[mf][nf] = MFMA16(af[mf], bf[nf], acc[mf][nf]);
        }
    }

    int sel = (n0 + wn * 32) >> 8;          // wave-uniform (32-col band within one 256-range)
    int ncb = (n0 + wn * 32) & 255;
    const float* bp = sel == 0 ? bq : (sel == 1 ? bk : bv);
    #pragma unroll
    for (int mf = 0; mf < 4; ++mf) {
        #pragma unroll
        for (int nf = 0; nf < 2; ++nf) {
            int nc = ncb + nf * 16 + lr;
            float bb = bp[nc];
            #pragma unroll
            for (int e = 0; e < 4; ++e) {
                int m = m0 + wm * 64 + mf * 16 + lg * 4 + e;
                float v = acc[mf][nf][e] + bb;
                if (sel < 2) {
                    float pv = __shfl_xor(v, 1, 64);   // partner column nc^1
                    int tok = m % NTOK;
                    int j = nc >> 1;
                    float c = cosb[tok * 128 + j], s = sinb[tok * 128 + j];
                    float o = (nc & 1) ? (pv * s + v * c) : (v * c - pv * s);
                    if (m < M) {
                        ushort* dst = sel == 0 ? qbf : kbf;
                        dst[(size_t)m * DMODEL + nc] = f2bf(o);
                    }
                } else if (m < M) {
                    int b_ = m / NTOK, tok = m - b_ * NTOK;
                    vT[((size_t)(b_ * 256 + nc)) * VSTR + tok] = f2bf(v);
                }
            }
        }
    }
}

// ---------------- GELU MFMA GEMM (128x128 tile, 512 threads / 8 waves, XCD-swizzled) ----------------
__global__ __launch_bounds__(512) void gemm_gelu(
    const ushort* __restrict__ A, const ushort* __restrict__ WT,
    const float* __restrict__ bias, ushort* __restrict__ Cbf, int M)
{
    __shared__ __align__(16) ushort As[128 * 64];
    __shared__ __align__(16) ushort Bs[128 * 64];
    int bid = blockIdx.x;
    int xcd = bid & 7, idx = bid >> 3;          // idx 0..135
    int mt = xcd * 17 + (idx >> 3);             // 0..135 (>=129 dead)
    int m0 = mt * 128;
    if (m0 >= M) return;
    int n0 = (idx & 7) * 128;
    int tid = threadIdx.x;                      // 0..511
    int w = tid >> 6, l = tid & 63;
    int lr = l & 15, lg = l >> 4;
    int wm = w & 1, wn = w >> 1;                // 2m x 4n waves
    int wb0 = (tid & ~63) * 16;
    f32x4 acc[4][2] = {};

    for (int k0 = 0; k0 < 256; k0 += 64) {
        __syncthreads();
        #pragma unroll
        for (int i = 0; i < 2; ++i) {
            int id = tid + 512 * i; int r = id >> 3, c8 = id & 7;
            int mrow = m0 + r; if (mrow > M - 1) mrow = M - 1;
            int c8s = c8 ^ (r & 7);
            gload16(A + (size_t)mrow * 256 + k0 + c8s * 8, (char*)As + wb0 + i * 8192);
        }
        #pragma unroll
        for (int i = 0; i < 2; ++i) {
            int id = tid + 512 * i; int r = id >> 3, c8 = id & 7;
            int c8s = c8 ^ (r & 7);
            gload16(WT + (size_t)(n0 + r) * 256 + k0 + c8s * 8, (char*)Bs + wb0 + i * 8192);
        }
        __syncthreads();
        #pragma unroll
        for (int ks = 0; ks < 2; ++ks) {
            bf16x8 af[4], bf[2];
            #pragma unroll
            for (int mf = 0; mf < 4; ++mf)
                af[mf] = *(const bf16x8*)((char*)As + swz16(wm * 64 + mf * 16 + lr, ks * 64 + lg * 16));
            #pragma unroll
            for (int nf = 0; nf < 2; ++nf)
                bf[nf] = *(const bf16x8*)((char*)Bs + swz16(wn * 32 + nf * 16 + lr, ks * 64 + lg * 16));
            #pragma unroll
            for (int nf = 0; nf < 2; ++nf)
                #pragma unroll
                for (int mf = 0; mf < 4; ++mf)
                    acc[mf][nf] = MFMA16(af[mf], bf[nf], acc[mf][nf]);
        }
    }

    #pragma unroll
    for (int mf = 0; mf < 4; ++mf) {
        #pragma unroll
        for (int nf = 0; nf < 2; ++nf) {
            int n = n0 + wn * 32 + nf * 16 + lr;
            float bb = bias[n];
            #pragma unroll
            for (int e = 0; e < 4; ++e) {
                int m = m0 + wm * 64 + mf * 16 + lg * 4 + e;
                float v = acc[mf][nf][e] + bb;
                if (m < M) {
                    // tanh-form GELU (|err| vs erf-form < ~1e-3, inside bf16 noise)
                    float u = 0.7978845608f * (v + 0.044715f * v * v * v);
                    float t = 1.0f - 2.0f / (__expf(2.0f * u) + 1.0f);
                    float gg = 0.5f * v * (1.0f + t);
                    Cbf[(size_t)m * HIDDEN + n] = f2bf(gg);
                }
            }
        }
    }
}

// ---------------- fused GEMM + residual + LayerNorm (64 rows x 256 cols, 512 threads / 8 waves) ----------------
__global__ __launch_bounds__(512) void gemm_res_ln(
    const ushort* __restrict__ A, const ushort* __restrict__ WT,
    const float* __restrict__ bias, float* __restrict__ hres,
    ushort* __restrict__ ybf, const float* __restrict__ g,
    const float* __restrict__ beta, int M, int K)
{
    __shared__ __align__(16) ushort As[64 * 64];    // 8 KB
    __shared__ __align__(16) ushort Bs[256 * 64];   // 32 KB
    __shared__ float psum[8][64], psq[8][64];
    __shared__ float mv[64][2];
    int tid = threadIdx.x;          // 0..511
    int w = tid >> 6, l = tid & 63; // 8 waves; wave w owns cols [w*32, w*32+32)
    int lr = l & 15, lg = l >> 4;
    int m0 = blockIdx.x * 64;
    int wb0 = (tid & ~63) * 16;     // 0..7168, 8 KB per staging round
    f32x4 acc[4][2] = {};

    for (int k0 = 0; k0 < K; k0 += 64) {
        __syncthreads();
        // A: 64 rows x 8 chunks = 512 chunks, one per thread
        {
            int r = tid >> 3, c8 = tid & 7;
            int mrow = m0 + r; if (mrow > M - 1) mrow = M - 1;
            int c8s = c8 ^ (r & 7);
            gload16(A + (size_t)mrow * K + k0 + c8s * 8, (char*)As + wb0);
        }
        // B: 256 rows x 8 chunks = 2048 chunks, 4 rounds of 512
        #pragma unroll
        for (int i = 0; i < 4; ++i) {
            int id = tid + 512 * i; int r = id >> 3, c8 = id & 7;
            int c8s = c8 ^ (r & 7);
            gload16(WT + (size_t)r * K + k0 + c8s * 8, (char*)Bs + wb0 + i * 8192);
        }
        __syncthreads();
        #pragma unroll
        for (int ks = 0; ks < 2; ++ks) {
            bf16x8 af[4], bf[2];
            #pragma unroll
            for (int mf = 0; mf < 4; ++mf)
                af[mf] = *(const bf16x8*)((char*)As + swz16(mf * 16 + lr, ks * 64 + lg * 16));
            #pragma unroll
            for (int nf = 0; nf < 2; ++nf)
                bf[nf] = *(const bf16x8*)((char*)Bs + swz16(w * 32 + nf * 16 + lr, ks * 64 + lg * 16));
            #pragma unroll
            for (int nf = 0; nf < 2; ++nf)
                #pragma unroll
                for (int mf = 0; mf < 4; ++mf)
                    acc[mf][nf] = MFMA16(af[mf], bf[nf], acc[mf][nf]);
        }
    }

    // epilogue: bias + residual into acc, then block-wide LN over the 256-wide rows
    #pragma unroll
    for (int mf = 0; mf < 4; ++mf) {
        #pragma unroll
        for (int nf = 0; nf < 2; ++nf) {
            int n = w * 32 + nf * 16 + lr;
            float bb = bias[n];
            #pragma unroll
            for (int e = 0; e < 4; ++e) {
                int m = m0 + mf * 16 + lg * 4 + e;
                float hv = acc[mf][nf][e] + bb;
                if (m < M) hv += hres[(size_t)m * DMODEL + n];
                acc[mf][nf][e] = hv;
            }
        }
    }
    #pragma unroll
    for (int mf = 0; mf < 4; ++mf) {
        #pragma unroll
        for (int e = 0; e < 4; ++e) {
            float s = acc[mf][0][e] + acc[mf][1][e];
            float q = acc[mf][0][e] * acc[mf][0][e] + acc[mf][1][e] * acc[mf][1][e];
            #pragma unroll
            for (int t = 1; t < 16; t <<= 1) {
                s += __shfl_xor(s, t, 16);
                q += __shfl_xor(q, t, 16);
            }
            if (lr == 0) {
                int r64 = mf * 16 + lg * 4 + e;
                psum[w][r64] = s;
                psq[w][r64] = q;
            }
        }
    }
    __syncthreads();
    if (tid < 64) {
        float s = 0.f, q = 0.f;
        #pragma unroll
        for (int ww = 0; ww < 8; ++ww) { s += psum[ww][tid]; q += psq[ww][tid]; }
        float mean = s * (1.0f / 256.0f);
        float var = q * (1.0f / 256.0f) - mean * mean;
        mv[tid][0] = mean;
        mv[tid][1] = rsqrtf(var + 1e-5f);
    }
    __syncthreads();
    #pragma unroll
    for (int mf = 0; mf < 4; ++mf) {
        #pragma unroll
        for (int e = 0; e < 4; ++e) {
            int r64 = mf * 16 + lg * 4 + e;
            int m = m0 + r64;
            if (m >= M) continue;
            float mean = mv[r64][0], rstd = mv[r64][1];
            #pragma unroll
            for (int nf = 0; nf < 2; ++nf) {
                int n = w * 32 + nf * 16 + lr;
                float hv = acc[mf][nf][e];
                hres[(size_t)m * DMODEL + n] = hv;
                ybf[(size_t)m * DMODEL + n] = f2bf((hv - mean) * rstd * g[n] + beta[n]);
            }
        }
    }
}

// ---------------- flash attention: XCD-swizzled, Q in regs, Ps aliases Qs (R9 winner) ----------------
// grid: 1088 linear; xcd owns 8 bh groups x 17 q-tiles
__global__ __launch_bounds__(256) void flash_mfma(
    const ushort* __restrict__ Qb, const ushort* __restrict__ Kb,
    const ushort* __restrict__ Vt, ushort* __restrict__ Ctx)
{
    __shared__ __align__(16) ushort QPs[64 * 64];     // Q staging, then P buffer
    __shared__ __align__(16) ushort Ks[2][64 * 64];
    __shared__ __align__(16) ushort Vs[2][64 * 64];

    int bid = blockIdx.x;
    int xcd = bid & 7, idx = bid >> 3;   // idx 0..135
    int bh = xcd * 8 + idx / 17;         // all 17 q-tiles of a bh on one XCD
    int q0 = (idx % 17) * 64;
    int tid = threadIdx.x;
    int w = tid >> 6, l = tid & 63;
    int lr = l & 15, lg = l >> 4;
    int b = bh >> 2, h = bh & 3;
    const size_t rowbase = (size_t)b * NTOK;
    const size_t vbase = (size_t)(b * 256 + h * 64) * VSTR;
    int wb0 = (tid & ~63) * 16;

    // stage Q tile (async)
    #pragma unroll
    for (int i = 0; i < 2; ++i) {
        int id = tid + 256 * i; int r = id >> 3, c8 = id & 7;
        int qr = q0 + r; if (qr > 1024) qr = 1024;
        int c8s = c8 ^ (r & 7);
        gload16(Qb + (rowbase + qr) * 256 + h * 64 + c8s * 8,
                (char*)QPs + wb0 + i * 4096);
    }

    auto stageKV = [&](int buf, int kt) {
        #pragma unroll
        for (int i = 0; i < 2; ++i) {
            int id = tid + 256 * i; int r = id >> 3, c8 = id & 7;
            int c8s = c8 ^ (r & 7);
            int kr = kt * 64 + r; int kcl = kr > 1024 ? 1024 : kr;
            gload16(Kb + (rowbase + kcl) * 256 + h * 64 + c8s * 8,
                    (char*)Ks[buf] + wb0 + i * 4096);
            gload16(Vt + vbase + (size_t)r * VSTR + kt * 64 + c8s * 8,
                    (char*)Vs[buf] + wb0 + i * 4096);
        }
    };

    stageKV(0, 0);
    __syncthreads();   // drains vmcnt -> Q + tile0 visible

    // hoist Q to registers (loop-invariant); QPs becomes the P buffer afterwards.
    bf16x8 qreg[2];
    #pragma unroll
    for (int ks = 0; ks < 2; ++ks)
        qreg[ks] = *(const bf16x8*)((char*)QPs + swz16(w * 16 + lr, ks * 64 + lg * 16));

    f32x4 po[4] = {};
    float lsum = 0.f;       // partial softmax denominator for q = q0 + w*16 + lr
    int cur = 0;

    for (int kt = 0; kt < 17; ++kt) {
        if (kt < 16) stageKV(cur ^ 1, kt + 1);   // async prefetch

        // S^T = K @ Q^T : lane holds q = lr, k = nf*16 + lg*4 + e
        f32x4 sa[4] = {};
        #pragma unroll
        for (int ks = 0; ks < 2; ++ks) {
            #pragma unroll
            for (int nf = 0; nf < 4; ++nf) {
                bf16x8 kb = *(const bf16x8*)((char*)Ks[cur] + swz16(nf * 16 + lr, ks * 64 + lg * 16));
                sa[nf] = MFMA16(kb, qreg[ks], sa[nf]);   // swapped operands
            }
        }

        // p = exp(S/8) (no max subtraction; |S| is O(1)); mask k>1024; pack to P
        #pragma unroll
        for (int nf = 0; nf < 4; ++nf) {
            float p0, p1, p2, p3;
            {
                int kc0 = kt * 64 + nf * 16 + lg * 4;
                p0 = (kc0 + 0 > 1024) ? 0.f : __expf(sa[nf][0] * 0.125f);
                p1 = (kc0 + 1 > 1024) ? 0.f : __expf(sa[nf][1] * 0.125f);
                p2 = (kc0 + 2 > 1024) ? 0.f : __expf(sa[nf][2] * 0.125f);
                p3 = (kc0 + 3 > 1024) ? 0.f : __expf(sa[nf][3] * 0.125f);
            }
            lsum += (p0 + p1) + (p2 + p3);
            uint2 t;
            t.x = pk2(f2bf(p0), f2bf(p1));
            t.y = pk2(f2bf(p2), f2bf(p3));
            *(uint2*)((char*)QPs + swz16(w * 16 + lr, nf * 32 + lg * 8)) = t;
        }

        // O += P @ V (wave-local P rows)
        #pragma unroll
        for (int ks = 0; ks < 2; ++ks) {
            bf16x8 pa = *(const bf16x8*)((char*)QPs + swz16(w * 16 + lr, ks * 64 + lg * 16));
            #pragma unroll
            for (int d = 0; d < 4; ++d) {
                bf16x8 vb = *(const bf16x8*)((char*)Vs[cur] + swz16(d * 16 + lr, ks * 64 + lg * 16));
                po[d] = MFMA16(pa, vb, po[d]);
            }
        }

        __syncthreads();   // prefetch landed; safe to flip
        cur ^= 1;
    }

    // final denominator reduce (across lg groups) + redistribute to po rows
    lsum += __shfl_xor(lsum, 16, 64);
    lsum += __shfl_xor(lsum, 32, 64);
    #pragma unroll
    for (int e = 0; e < 4; ++e) {
        float le = __shfl(lsum, lg * 4 + e, 16);   // l for q-row lg*4+e of this wave
        int qr = q0 + w * 16 + lg * 4 + e;
        if (qr <= 1024) {
            float inv = 1.0f / le;
            #pragma unroll
            for (int d = 0; d < 4; ++d)
                Ctx[(rowbase + qr) * 256 + h * 64 + d * 16 + lr] = f2bf(po[d][e] * inv);
        }
    }
}

// ---------------- classifier head (bf16 cls rows) ----------------
__global__ void head_kernel(const ushort* __restrict__ ybf,
                            const float* __restrict__ hw,
                            const float* __restrict__ hb,
                            float* __restrict__ out)
{
    int i = blockIdx.x * 256 + threadIdx.x;
    if (i >= BATCH * NCLS) return;
    int b = i / NCLS, c = i % NCLS;
    const ushort* xr = ybf + (size_t)b * NTOK * DMODEL;   // cls row of batch b
    float acc = hb[c];
    for (int t = 0; t < DMODEL; ++t) acc += bf2f(xr[t]) * hw[t * NCLS + c];
    out[i] = acc;
}

// ---------------- launch ----------------
extern "C" void kernel_launch(void* const* d_in, const int* in_sizes, int n_in,
                              void* d_out, int out_size, void* d_ws, size_t ws_size,
                              hipStream_t stream) {
    const float* x      = (const float*)d_in[0];
    const float* conv_w = (const float*)d_in[1];
    const float* conv_b = (const float*)d_in[2];
    const float* cls_tok= (const float*)d_in[3];
    const float* ln1_g  = (const float*)d_in[4];
    const float* ln1_b  = (const float*)d_in[5];
    const float* wq     = (const float*)d_in[6];
    const float* bq     = (const float*)d_in[7];
    const float* wk     = (const float*)d_in[8];
    const float* bk     = (const float*)d_in[9];
    const float* wv     = (const float*)d_in[10];
    const float* bv     = (const float*)d_in[11];
    const float* wo     = (const float*)d_in[12];
    const float* bo     = (const float*)d_in[13];
    const float* ln2_g  = (const float*)d_in[14];
    const float* ln2_b  = (const float*)d_in[15];
    const float* w1     = (const float*)d_in[16];
    const float* b1     = (const float*)d_in[17];
    const float* w2     = (const float*)d_in[18];
    const float* b2     = (const float*)d_in[19];
    const float* lnf_g  = (const float*)d_in[20];
    const float* lnf_b  = (const float*)d_in[21];
    const float* head_w = (const float*)d_in[22];
    const float* head_b = (const float*)d_in[23];

    char* p = (char*)d_ws;
    float* h    = (float*)p;            p += (size_t)NROWS * DMODEL * 4;
    float* cosb = (float*)p;            p += (size_t)NTOK * 128 * 4;
    float* sinb = (float*)p;            p += (size_t)NTOK * 128 * 4;
    ushort* ybf = (ushort*)p;           p += (size_t)NROWS * DMODEL * 2;
    ushort* cbf = (ushort*)p;           p += (size_t)NROWS * DMODEL * 2;
    ushort* qbf = (ushort*)p;           p += (size_t)NROWS * DMODEL * 2;
    ushort* kbf = (ushort*)p;           p += (size_t)NROWS * DMODEL * 2;
    ushort* vT  = (ushort*)p;           p += (size_t)BATCH * 256 * VSTR * 2 + 256;
    ushort* hidbf = (ushort*)p;         p += (size_t)NROWS * HIDDEN * 2;
    ushort* wqkvT = (ushort*)p;         p += (size_t)LAYERS * 768 * DMODEL * 2;
    ushort* woT = (ushort*)p;           p += (size_t)LAYERS * DMODEL * DMODEL * 2;
    ushort* w1T = (ushort*)p;           p += (size_t)LAYERS * DMODEL * HIDDEN * 2;
    ushort* w2T = (ushort*)p;           p += (size_t)LAYERS * DMODEL * HIDDEN * 2;
    ushort* cwb = (ushort*)p;           p += (size_t)DMODEL * 768 * 2;

    // one-time prep (deterministic, every call) — separate kernels (merged variant crashes)
    transpose_cvt_kernel<<<dim3(8, 8, LAYERS), 256, 0, stream>>>(
        wq, wqkvT, 256, 256, 65536, 196608);
    transpose_cvt_kernel<<<dim3(8, 8, LAYERS), 256, 0, stream>>>(
        wk, wqkvT + 65536, 256, 256, 65536, 196608);
    transpose_cvt_kernel<<<dim3(8, 8, LAYERS), 256, 0, stream>>>(
        wv, wqkvT + 131072, 256, 256, 65536, 196608);
    transpose_cvt_kernel<<<dim3(8, 8, LAYERS), 256, 0, stream>>>(
        wo, woT, 256, 256, 65536, 65536);
    transpose_cvt_kernel<<<dim3(32, 8, LAYERS), 256, 0, stream>>>(
        w1, w1T, 256, 1024, 262144, 262144);
    transpose_cvt_kernel<<<dim3(8, 32, LAYERS), 256, 0, stream>>>(
        w2, w2T, 1024, 256, 262144, 262144);
    rope_tab_kernel<<<(NTOK * 128 + 255) / 256, 256, 0, stream>>>(cosb, sinb);
    cls_kernel<<<BATCH, 256, 0, stream>>>(cls_tok, h);
    cvt_bf16_kernel<<<192, 256, 0, stream>>>(conv_w, cwb, DMODEL * 768);
    patch_gemm<<<512, 256, 0, stream>>>(x, cwb, conv_b, h);

    const int M = NROWS;
    int grln = (M + 63) / 64;

    // layer-0 LN1
    ln_kernel<<<(M + 3) / 4, 256, 0, stream>>>(h, ybf, ln1_g, ln1_b, M);

    for (int l = 0; l < LAYERS; ++l) {
        const ushort* WqkvT = wqkvT + (size_t)l * 768 * DMODEL;
        const ushort* WoT = woT + (size_t)l * DMODEL * DMODEL;
        const ushort* W1T = w1T + (size_t)l * DMODEL * HIDDEN;
        const ushort* W2T = w2T + (size_t)l * DMODEL * HIDDEN;

        gemm_qkv<<<816, 512, 0, stream>>>(ybf, WqkvT, bq + l * DMODEL, bk + l * DMODEL,
                                          bv + l * DMODEL, qbf, kbf, vT, cosb, sinb, M);
        flash_mfma<<<1088, 256, 0, stream>>>(qbf, kbf, vT, cbf);
        // h += ctx@Wo + bo ; ybf = LN2(h)
        gemm_res_ln<<<grln, 512, 0, stream>>>(cbf, WoT, bo + l * DMODEL, h, ybf,
                                              ln2_g + l * DMODEL, ln2_b + l * DMODEL,
                                              M, DMODEL);
        gemm_gelu<<<1088, 512, 0, stream>>>(ybf, W1T, b1 + l * HIDDEN, hidbf, M);
        // h += hid@W2 + b2 ; ybf = LN1_{l+1}(h)  (last layer: LNf)
        const float* ng = (l < LAYERS - 1) ? ln1_g + (l + 1) * DMODEL : lnf_g;
        const float* nb = (l < LAYERS - 1) ? ln1_b + (l + 1) * DMODEL : lnf_b;
        gemm_res_ln<<<grln, 512, 0, stream>>>(hidbf, W2T, b2 + l * DMODEL, h, ybf,
                                              ng, nb, M, HIDDEN);
    }
    head_kernel<<<(BATCH * NCLS + 255) / 256, 256, 0, stream>>>(ybf, head_w, head_b,
                                                                (float*)d_out);
}

// Round 17
// 1233.633 us; speedup vs baseline: 1.0536x; 1.0536x over previous
//
#include <hip/hip_runtime.h>
#include <hip/hip_bf16.h>
#include <math.h>

// ---------------- constants ----------------
#define BATCH 16
#define CIN 3
#define SIMG 512
#define PPATCH 16
#define DMODEL 256
#define HIDDEN 1024
#define LAYERS 8
#define NHEADS 4
#define DHEAD 64
#define NTOK 1025            // 1024 patches + cls
#define NROWS (BATCH * NTOK) // 16400
#define NCLS 1000
#define VSTR 1032            // padded token stride for vT (16B-aligned rows)

typedef __attribute__((ext_vector_type(8))) short bf16x8;
typedef __attribute__((ext_vector_type(4))) float f32x4;

#define MFMA16(a, b, c) __builtin_amdgcn_mfma_f32_16x16x32_bf16(a, b, c, 0, 0, 0)

__device__ __forceinline__ ushort f2bf(float f) {
    union { float f; unsigned u; } v; v.f = f;
    unsigned r = v.u + 0x7fff + ((v.u >> 16) & 1);
    return (ushort)(r >> 16);
}
__device__ __forceinline__ float bf2f(ushort u) {
    union { unsigned u; float f; } v; v.u = ((unsigned)u) << 16;
    return v.f;
}
__device__ __forceinline__ unsigned pk2(ushort a, ushort b) {
    return (unsigned)a | ((unsigned)b << 16);
}
// byte offset into a [rows][64]-bf16 LDS tile (128B rows), XOR-swizzled
__device__ __forceinline__ int swz16(int row, int bcol) {
    return row * 128 + (bcol ^ ((row & 7) << 4));
}
// async global->LDS, 16B per lane. LDS dest = wave-uniform base + lane*16.
__device__ __forceinline__ void gload16(const void* g, void* l) {
    __builtin_amdgcn_global_load_lds(
        (const __attribute__((address_space(1))) unsigned int*)g,
        (__attribute__((address_space(3))) unsigned int*)l,
        16, 0, 0);
}

// ---------------- RoPE tables ----------------
__global__ void rope_tab_kernel(float* __restrict__ cosb, float* __restrict__ sinb) {
    int i = blockIdx.x * 256 + threadIdx.x;
    if (i >= NTOK * 128) return;
    int n = i >> 7, j = i & 127;
    float inv = powf(10000.0f, -(float)(2 * j) / 256.0f);
    float ang = (float)n * inv;
    cosb[i] = cosf(ang);
    sinb[i] = sinf(ang);
}

// ---------------- cls token broadcast ----------------
__global__ void cls_kernel(const float* __restrict__ cls, float* __restrict__ tok) {
    int i = blockIdx.x * 256 + threadIdx.x;
    int b = i >> 8, d = i & 255;
    tok[(size_t)b * NTOK * DMODEL + d] = cls[d];
}

// ---------------- bf16 convert (conv weight, already [N][K]) ----------------
__global__ void cvt_bf16_kernel(const float* __restrict__ in, ushort* __restrict__ out, int n) {
    int base = (blockIdx.x * 256 + threadIdx.x) * 4;
    if (base >= n) return;
    float4 v = *(const float4*)(in + base);
    *(ushort4*)(out + base) = make_ushort4(f2bf(v.x), f2bf(v.y), f2bf(v.z), f2bf(v.w));
}

// ---------------- weight transpose + bf16 convert: WT[n][k] = bf16(W[k][n]) ----------------
__global__ __launch_bounds__(256) void transpose_cvt_kernel(
    const float* __restrict__ W, ushort* __restrict__ WT, int K, int N,
    long wl, long wtl)
{
    __shared__ float t[32][33];
    int l = blockIdx.z;
    W  += (size_t)l * wl;
    WT += (size_t)l * wtl;
    int kb = blockIdx.y * 32, nb = blockIdx.x * 32;
    int tx = threadIdx.x & 31, ty = threadIdx.x >> 5;
    #pragma unroll
    for (int i = 0; i < 32; i += 8)
        t[ty + i][tx] = W[(size_t)(kb + ty + i) * N + nb + tx];
    __syncthreads();
    #pragma unroll
    for (int i = 0; i < 32; i += 8)
        WT[(size_t)(nb + ty + i) * K + kb + tx] = f2bf(t[tx][ty + i]);
}

// ---------------- layernorm (used once, for layer-0 LN1) ----------------
__global__ __launch_bounds__(256) void ln_kernel(
    const float* __restrict__ in, ushort* __restrict__ outp,
    const float* __restrict__ g, const float* __restrict__ bta, int nrows)
{
    int row = blockIdx.x * 4 + (threadIdx.x >> 6);
    int lane = threadIdx.x & 63;
    if (row >= nrows) return;
    const float* xr = in + (size_t)row * DMODEL;
    float4 v = *(const float4*)(xr + lane * 4);
    float s = v.x + v.y + v.z + v.w;
    float ss = v.x * v.x + v.y * v.y + v.z * v.z + v.w * v.w;
    #pragma unroll
    for (int m = 1; m < 64; m <<= 1) {
        s += __shfl_xor(s, m, 64);
        ss += __shfl_xor(ss, m, 64);
    }
    float mean = s * (1.0f / 256.0f);
    float var = ss * (1.0f / 256.0f) - mean * mean;
    float inv = rsqrtf(var + 1e-5f);
    float4 gv = *(const float4*)(g + lane * 4);
    float4 bv = *(const float4*)(bta + lane * 4);
    ushort4 o = make_ushort4(f2bf((v.x - mean) * inv * gv.x + bv.x),
                             f2bf((v.y - mean) * inv * gv.y + bv.y),
                             f2bf((v.z - mean) * inv * gv.z + bv.z),
                             f2bf((v.w - mean) * inv * gv.w + bv.w));
    *(ushort4*)(outp + (size_t)row * DMODEL + lane * 4) = o;
}

// ---------------- patch embed as MFMA GEMM (fused im2col, XCD-swizzled) ----------------
__global__ __launch_bounds__(256) void patch_gemm(
    const float* __restrict__ x, const ushort* __restrict__ Wb,
    const float* __restrict__ bias, float* __restrict__ h)
{
    __shared__ __align__(16) ushort As[128 * 64];
    __shared__ __align__(16) ushort Bs[64 * 64];
    int bid = blockIdx.x;
    int xcd = bid & 7, idx = bid >> 3;          // idx 0..63
    int m0 = (xcd * 16 + (idx >> 2)) * 128;     // m-tile 0..127
    int n0 = (idx & 3) * 64;
    int tid = threadIdx.x;
    int w = tid >> 6, l = tid & 63;
    int lr = l & 15, lg = l >> 4;
    int wm = w & 1, wn = w >> 1;
    f32x4 acc[4][2] = {};

    for (int k0 = 0; k0 < 768; k0 += 64) {
        __syncthreads();
        #pragma unroll
        for (int i = 0; i < 4; ++i) {
            int id = tid + 256 * i; int r = id >> 3, c8 = id & 7;
            int m = m0 + r;
            int b_ = m >> 10, pi = m & 1023, ph = pi >> 5, pw = pi & 31;
            int k = k0 + c8 * 8;
            int c = k >> 8, rem = k & 255, pr = rem >> 4, q = rem & 15;
            const float* src = x + ((size_t)((b_ * 3 + c) * SIMG) + ph * 16 + pr) * SIMG
                                 + pw * 16 + q;
            float4 v0 = *(const float4*)src;
            float4 v1 = *(const float4*)(src + 4);
            uint4 t;
            t.x = pk2(f2bf(v0.x), f2bf(v0.y));
            t.y = pk2(f2bf(v0.z), f2bf(v0.w));
            t.z = pk2(f2bf(v1.x), f2bf(v1.y));
            t.w = pk2(f2bf(v1.z), f2bf(v1.w));
            *(uint4*)((char*)As + swz16(r, c8 * 16)) = t;
        }
        #pragma unroll
        for (int i = 0; i < 2; ++i) {
            int id = tid + 256 * i; int r = id >> 3, c8 = id & 7;
            uint4 t = *(const uint4*)(Wb + (size_t)(n0 + r) * 768 + k0 + c8 * 8);
            *(uint4*)((char*)Bs + swz16(r, c8 * 16)) = t;
        }
        __syncthreads();
        #pragma unroll
        for (int ks = 0; ks < 2; ++ks) {
            bf16x8 af[4];
            #pragma unroll
            for (int mf = 0; mf < 4; ++mf)
                af[mf] = *(const bf16x8*)((char*)As + swz16(wm * 64 + mf * 16 + lr, ks * 64 + lg * 16));
            #pragma unroll
            for (int nf = 0; nf < 2; ++nf) {
                bf16x8 bfr = *(const bf16x8*)((char*)Bs + swz16(wn * 32 + nf * 16 + lr, ks * 64 + lg * 16));
                #pragma unroll
                for (int mf = 0; mf < 4; ++mf)
                    acc[mf][nf] = MFMA16(af[mf], bfr, acc[mf][nf]);
            }
        }
    }
    #pragma unroll
    for (int mf = 0; mf < 4; ++mf) {
        #pragma unroll
        for (int nf = 0; nf < 2; ++nf) {
            int n = n0 + wn * 32 + nf * 16 + lr;
            float bb = bias[n];
            #pragma unroll
            for (int e = 0; e < 4; ++e) {
                int m = m0 + wm * 64 + mf * 16 + lg * 4 + e;
                int b_ = m >> 10, pi = m & 1023;
                h[((size_t)(b_ * NTOK + 1 + pi)) * DMODEL + n] = acc[mf][nf][e] + bb;
            }
        }
    }
}

// ---------------- fused QKV MFMA GEMM (128x128 tile, 512 threads / 8 waves, XCD-swizzled) ----------------
__global__ __launch_bounds__(512) void gemm_qkv(
    const ushort* __restrict__ A, const ushort* __restrict__ WT,
    const float* __restrict__ bq, const float* __restrict__ bk,
    const float* __restrict__ bv,
    ushort* __restrict__ qbf, ushort* __restrict__ kbf, ushort* __restrict__ vT,
    const float* __restrict__ cosb, const float* __restrict__ sinb, int M)
{
    __shared__ __align__(16) ushort As[128 * 64];
    __shared__ __align__(16) ushort Bs[128 * 64];
    int bid = blockIdx.x;
    int xcd = bid & 7, idx = bid >> 3;          // idx 0..101
    int mt = xcd * 17 + idx / 6;                // 0..135 (>=129 dead)
    int m0 = mt * 128;
    if (m0 >= M) return;
    int n0 = (idx % 6) * 128;
    int tid = threadIdx.x;                      // 0..511
    int w = tid >> 6, l = tid & 63;
    int lr = l & 15, lg = l >> 4;
    int wm = w & 1, wn = w >> 1;                // 2m x 4n waves; wave = 64 x 32
    int wb0 = (tid & ~63) * 16;
    f32x4 acc[4][2] = {};

    for (int k0 = 0; k0 < 256; k0 += 64) {
        __syncthreads();
        #pragma unroll
        for (int i = 0; i < 2; ++i) {
            int id = tid + 512 * i; int r = id >> 3, c8 = id & 7;
            int mrow = m0 + r; if (mrow > M - 1) mrow = M - 1;
            int c8s = c8 ^ (r & 7);
            gload16(A + (size_t)mrow * 256 + k0 + c8s * 8, (char*)As + wb0 + i * 8192);
        }
        #pragma unroll
        for (int i = 0; i < 2; ++i) {
            int id = tid + 512 * i; int r = id >> 3, c8 = id & 7;
            int c8s = c8 ^ (r & 7);
            gload16(WT + (size_t)(n0 + r) * 256 + k0 + c8s * 8, (char*)Bs + wb0 + i * 8192);
        }
        __syncthreads();
        #pragma unroll
        for (int ks = 0; ks < 2; ++ks) {
            bf16x8 af[4], bf[2];
            #pragma unroll
            for (int mf = 0; mf < 4; ++mf)
                af[mf] = *(const bf16x8*)((char*)As + swz16(wm * 64 + mf * 16 + lr, ks * 64 + lg * 16));
            #pragma unroll
            for (int nf = 0; nf < 2; ++nf)
                bf[nf] = *(const bf16x8*)((char*)Bs + swz16(wn * 32 + nf * 16 + lr, ks * 64 + lg * 16));
            #pragma unroll
            for (int nf = 0; nf < 2; ++nf)
                #pragma unroll
                for (int mf = 0; mf < 4; ++mf)
                    acc[mf][nf] = MFMA16(af[mf], bf[nf], acc[mf][nf]);
        }
    }

    int sel = (n0 + wn * 32) >> 8;          // wave-uniform (32-col band within one 256-range)
    int ncb = (n0 + wn * 32) & 255;
    const float* bp = sel == 0 ? bq : (sel == 1 ? bk : bv);
    #pragma unroll
    for (int mf = 0; mf < 4; ++mf) {
        #pragma unroll
        for (int nf = 0; nf < 2; ++nf) {
            int nc = ncb + nf * 16 + lr;
            float bb = bp[nc];
            #pragma unroll
            for (int e = 0; e < 4; ++e) {
                int m = m0 + wm * 64 + mf * 16 + lg * 4 + e;
                float v = acc[mf][nf][e] + bb;
                if (sel < 2) {
                    float pv = __shfl_xor(v, 1, 64);   // partner column nc^1
                    int tok = m % NTOK;
                    int j = nc >> 1;
                    float c = cosb[tok * 128 + j], s = sinb[tok * 128 + j];
                    float o = (nc & 1) ? (pv * s + v * c) : (v * c - pv * s);
                    if (m < M) {
                        ushort* dst = sel == 0 ? qbf : kbf;
                        dst[(size_t)m * DMODEL + nc] = f2bf(o);
                    }
                } else if (m < M) {
                    int b_ = m / NTOK, tok = m - b_ * NTOK;
                    vT[((size_t)(b_ * 256 + nc)) * VSTR + tok] = f2bf(v);
                }
            }
        }
    }
}

// ---------------- GELU MFMA GEMM (128x128 tile, 512 threads / 8 waves, XCD-swizzled) ----------------
__global__ __launch_bounds__(512) void gemm_gelu(
    const ushort* __restrict__ A, const ushort* __restrict__ WT,
    const float* __restrict__ bias, ushort* __restrict__ Cbf, int M)
{
    __shared__ __align__(16) ushort As[128 * 64];
    __shared__ __align__(16) ushort Bs[128 * 64];
    int bid = blockIdx.x;
    int xcd = bid & 7, idx = bid >> 3;          // idx 0..135
    int mt = xcd * 17 + (idx >> 3);             // 0..135 (>=129 dead)
    int m0 = mt * 128;
    if (m0 >= M) return;
    int n0 = (idx & 7) * 128;
    int tid = threadIdx.x;                      // 0..511
    int w = tid >> 6, l = tid & 63;
    int lr = l & 15, lg = l >> 4;
    int wm = w & 1, wn = w >> 1;                // 2m x 4n waves
    int wb0 = (tid & ~63) * 16;
    f32x4 acc[4][2] = {};

    for (int k0 = 0; k0 < 256; k0 += 64) {
        __syncthreads();
        #pragma unroll
        for (int i = 0; i < 2; ++i) {
            int id = tid + 512 * i; int r = id >> 3, c8 = id & 7;
            int mrow = m0 + r; if (mrow > M - 1) mrow = M - 1;
            int c8s = c8 ^ (r & 7);
            gload16(A + (size_t)mrow * 256 + k0 + c8s * 8, (char*)As + wb0 + i * 8192);
        }
        #pragma unroll
        for (int i = 0; i < 2; ++i) {
            int id = tid + 512 * i; int r = id >> 3, c8 = id & 7;
            int c8s = c8 ^ (r & 7);
            gload16(WT + (size_t)(n0 + r) * 256 + k0 + c8s * 8, (char*)Bs + wb0 + i * 8192);
        }
        __syncthreads();
        #pragma unroll
        for (int ks = 0; ks < 2; ++ks) {
            bf16x8 af[4], bf[2];
            #pragma unroll
            for (int mf = 0; mf < 4; ++mf)
                af[mf] = *(const bf16x8*)((char*)As + swz16(wm * 64 + mf * 16 + lr, ks * 64 + lg * 16));
            #pragma unroll
            for (int nf = 0; nf < 2; ++nf)
                bf[nf] = *(const bf16x8*)((char*)Bs + swz16(wn * 32 + nf * 16 + lr, ks * 64 + lg * 16));
            #pragma unroll
            for (int nf = 0; nf < 2; ++nf)
                #pragma unroll
                for (int mf = 0; mf < 4; ++mf)
                    acc[mf][nf] = MFMA16(af[mf], bf[nf], acc[mf][nf]);
        }
    }

    #pragma unroll
    for (int mf = 0; mf < 4; ++mf) {
        #pragma unroll
        for (int nf = 0; nf < 2; ++nf) {
            int n = n0 + wn * 32 + nf * 16 + lr;
            float bb = bias[n];
            #pragma unroll
            for (int e = 0; e < 4; ++e) {
                int m = m0 + wm * 64 + mf * 16 + lg * 4 + e;
                float v = acc[mf][nf][e] + bb;
                if (m < M) {
                    float gg = 0.5f * v * (1.0f + erff(v * 0.70710678118f));
                    Cbf[(size_t)m * HIDDEN + n] = f2bf(gg);
                }
            }
        }
    }
}

// ---------------- fused GEMM + residual + LayerNorm (64 rows x 256 cols, 512 threads / 8 waves) ----------------
__global__ __launch_bounds__(512) void gemm_res_ln(
    const ushort* __restrict__ A, const ushort* __restrict__ WT,
    const float* __restrict__ bias, float* __restrict__ hres,
    ushort* __restrict__ ybf, const float* __restrict__ g,
    const float* __restrict__ beta, int M, int K)
{
    __shared__ __align__(16) ushort As[64 * 64];    // 8 KB
    __shared__ __align__(16) ushort Bs[256 * 64];   // 32 KB
    __shared__ float psum[8][64], psq[8][64];
    __shared__ float mv[64][2];
    int tid = threadIdx.x;          // 0..511
    int w = tid >> 6, l = tid & 63; // 8 waves; wave w owns cols [w*32, w*32+32)
    int lr = l & 15, lg = l >> 4;
    int m0 = blockIdx.x * 64;
    int wb0 = (tid & ~63) * 16;     // 0..7168, 8 KB per staging round
    f32x4 acc[4][2] = {};

    for (int k0 = 0; k0 < K; k0 += 64) {
        __syncthreads();
        // A: 64 rows x 8 chunks = 512 chunks, one per thread
        {
            int r = tid >> 3, c8 = tid & 7;
            int mrow = m0 + r; if (mrow > M - 1) mrow = M - 1;
            int c8s = c8 ^ (r & 7);
            gload16(A + (size_t)mrow * K + k0 + c8s * 8, (char*)As + wb0);
        }
        // B: 256 rows x 8 chunks = 2048 chunks, 4 rounds of 512
        #pragma unroll
        for (int i = 0; i < 4; ++i) {
            int id = tid + 512 * i; int r = id >> 3, c8 = id & 7;
            int c8s = c8 ^ (r & 7);
            gload16(WT + (size_t)r * K + k0 + c8s * 8, (char*)Bs + wb0 + i * 8192);
        }
        __syncthreads();
        #pragma unroll
        for (int ks = 0; ks < 2; ++ks) {
            bf16x8 af[4], bf[2];
            #pragma unroll
            for (int mf = 0; mf < 4; ++mf)
                af[mf] = *(const bf16x8*)((char*)As + swz16(mf * 16 + lr, ks * 64 + lg * 16));
            #pragma unroll
            for (int nf = 0; nf < 2; ++nf)
                bf[nf] = *(const bf16x8*)((char*)Bs + swz16(w * 32 + nf * 16 + lr, ks * 64 + lg * 16));
            #pragma unroll
            for (int nf = 0; nf < 2; ++nf)
                #pragma unroll
                for (int mf = 0; mf < 4; ++mf)
                    acc[mf][nf] = MFMA16(af[mf], bf[nf], acc[mf][nf]);
        }
    }

    // epilogue: bias + residual into acc, then block-wide LN over the 256-wide rows
    #pragma unroll
    for (int mf = 0; mf < 4; ++mf) {
        #pragma unroll
        for (int nf = 0; nf < 2; ++nf) {
            int n = w * 32 + nf * 16 + lr;
            float bb = bias[n];
            #pragma unroll
            for (int e = 0; e < 4; ++e) {
                int m = m0 + mf * 16 + lg * 4 + e;
                float hv = acc[mf][nf][e] + bb;
                if (m < M) hv += hres[(size_t)m * DMODEL + n];
                acc[mf][nf][e] = hv;
            }
        }
    }
    #pragma unroll
    for (int mf = 0; mf < 4; ++mf) {
        #pragma unroll
        for (int e = 0; e < 4; ++e) {
            float s = acc[mf][0][e] + acc[mf][1][e];
            float q = acc[mf][0][e] * acc[mf][0][e] + acc[mf][1][e] * acc[mf][1][e];
            #pragma unroll
            for (int t = 1; t < 16; t <<= 1) {
                s += __shfl_xor(s, t, 16);
                q += __shfl_xor(q, t, 16);
            }
            if (lr == 0) {
                int r64 = mf * 16 + lg * 4 + e;
                psum[w][r64] = s;
                psq[w][r64] = q;
            }
        }
    }
    __syncthreads();
    if (tid < 64) {
        float s = 0.f, q = 0.f;
        #pragma unroll
        for (int ww = 0; ww < 8; ++ww) { s += psum[ww][tid]; q += psq[ww][tid]; }
        float mean = s * (1.0f / 256.0f);
        float var = q * (1.0f / 256.0f) - mean * mean;
        mv[tid][0] = mean;
        mv[tid][1] = rsqrtf(var + 1e-5f);
    }
    __syncthreads();
    #pragma unroll
    for (int mf = 0; mf < 4; ++mf) {
        #pragma unroll
        for (int e = 0; e < 4; ++e) {
            int r64 = mf * 16 + lg * 4 + e;
            int m = m0 + r64;
            if (m >= M) continue;
            float mean = mv[r64][0], rstd = mv[r64][1];
            #pragma unroll
            for (int nf = 0; nf < 2; ++nf) {
                int n = w * 32 + nf * 16 + lr;
                float hv = acc[mf][nf][e];
                hres[(size_t)m * DMODEL + n] = hv;
                ybf[(size_t)m * DMODEL + n] = f2bf((hv - mean) * rstd * g[n] + beta[n]);
            }
        }
    }
}

// ---------------- flash attention: T14 reg-staged K/V (24 KB LDS), XCD-swizzled ----------------
// grid: 1088 linear; xcd owns 8 bh groups x 17 q-tiles
__global__ __launch_bounds__(256) void flash_mfma(
    const ushort* __restrict__ Qb, const ushort* __restrict__ Kb,
    const ushort* __restrict__ Vt, ushort* __restrict__ Ctx)
{
    __shared__ __align__(16) ushort QPs[64 * 64];     // Q staging, then P buffer (8 KB)
    __shared__ __align__(16) ushort Ks[64 * 64];      // single buffer (8 KB)
    __shared__ __align__(16) ushort Vs[64 * 64];      // single buffer (8 KB)

    int bid = blockIdx.x;
    int xcd = bid & 7, idx = bid >> 3;   // idx 0..135
    int bh = xcd * 8 + idx / 17;         // all 17 q-tiles of a bh on one XCD
    int q0 = (idx % 17) * 64;
    int tid = threadIdx.x;
    int w = tid >> 6, l = tid & 63;
    int lr = l & 15, lg = l >> 4;
    int b = bh >> 2, h = bh & 3;
    const size_t rowbase = (size_t)b * NTOK;
    const size_t vbase = (size_t)(b * 256 + h * 64) * VSTR;
    int wb0 = (tid & ~63) * 16;

    // per-thread staging geometry: two 16B chunks (rows r0/r1, linear cols)
    int id0 = tid, id1 = tid + 256;
    int r0 = id0 >> 3, c80 = id0 & 7;
    int r1 = id1 >> 3, c81 = id1 & 7;
    int d0 = swz16(r0, c80 * 16), d1 = swz16(r1, c81 * 16);   // swizzled LDS dests

    // stage Q tile (async; linear source matching linear gload dest then swizzled read?
    // NO — keep Q path identical to R14: pre-swizzled source + linear LDS dest)
    {
        int qr0 = q0 + r0; if (qr0 > 1024) qr0 = 1024;
        int qr1 = q0 + r1; if (qr1 > 1024) qr1 = 1024;
        int c80s = c80 ^ (r0 & 7), c81s = c81 ^ (r1 & 7);
        gload16(Qb + (rowbase + qr0) * 256 + h * 64 + c80s * 8, (char*)QPs + wb0);
        gload16(Qb + (rowbase + qr1) * 256 + h * 64 + c81s * 8, (char*)QPs + wb0 + 4096);
    }

    // register staging of K/V tiles (global -> reg, reg -> swizzled LDS)
    uint4 kreg0, kreg1, vreg0, vreg1;
    auto loadKV = [&](int kt) {
        int kr0 = kt * 64 + r0; if (kr0 > 1024) kr0 = 1024;
        int kr1 = kt * 64 + r1; if (kr1 > 1024) kr1 = 1024;
        kreg0 = *(const uint4*)(Kb + (rowbase + kr0) * 256 + h * 64 + c80 * 8);
        kreg1 = *(const uint4*)(Kb + (rowbase + kr1) * 256 + h * 64 + c81 * 8);
        vreg0 = *(const uint4*)(Vt + vbase + (size_t)r0 * VSTR + kt * 64 + c80 * 8);
        vreg1 = *(const uint4*)(Vt + vbase + (size_t)r1 * VSTR + kt * 64 + c81 * 8);
    };
    auto writeKV = [&]() {
        *(uint4*)((char*)Ks + d0) = kreg0;
        *(uint4*)((char*)Ks + d1) = kreg1;
        *(uint4*)((char*)Vs + d0) = vreg0;
        *(uint4*)((char*)Vs + d1) = vreg1;
    };

    loadKV(0);
    __syncthreads();            // drains Q gload vmcnt
    writeKV();                  // tile 0 into LDS
    __syncthreads();            // K/V tile 0 visible

    // hoist Q to registers (loop-invariant); QPs becomes the P buffer afterwards.
    bf16x8 qreg[2];
    #pragma unroll
    for (int ks = 0; ks < 2; ++ks)
        qreg[ks] = *(const bf16x8*)((char*)QPs + swz16(w * 16 + lr, ks * 64 + lg * 16));

    f32x4 po[4] = {};
    float lsum = 0.f;       // partial softmax denominator for q = q0 + w*16 + lr

    for (int kt = 0; kt < 17; ++kt) {
        if (kt < 16) loadKV(kt + 1);   // issue next-tile global loads early (latency hides under compute)

        // S^T = K @ Q^T : lane holds q = lr, k = nf*16 + lg*4 + e
        f32x4 sa[4] = {};
        #pragma unroll
        for (int ks = 0; ks < 2; ++ks) {
            #pragma unroll
            for (int nf = 0; nf < 4; ++nf) {
                bf16x8 kb = *(const bf16x8*)((char*)Ks + swz16(nf * 16 + lr, ks * 64 + lg * 16));
                sa[nf] = MFMA16(kb, qreg[ks], sa[nf]);   // swapped operands
            }
        }

        // p = exp(S/8) (no max subtraction; |S| is O(1)); mask k>1024; pack to P
        #pragma unroll
        for (int nf = 0; nf < 4; ++nf) {
            float p0, p1, p2, p3;
            {
                int kc0 = kt * 64 + nf * 16 + lg * 4;
                p0 = (kc0 + 0 > 1024) ? 0.f : __expf(sa[nf][0] * 0.125f);
                p1 = (kc0 + 1 > 1024) ? 0.f : __expf(sa[nf][1] * 0.125f);
                p2 = (kc0 + 2 > 1024) ? 0.f : __expf(sa[nf][2] * 0.125f);
                p3 = (kc0 + 3 > 1024) ? 0.f : __expf(sa[nf][3] * 0.125f);
            }
            lsum += (p0 + p1) + (p2 + p3);
            uint2 t;
            t.x = pk2(f2bf(p0), f2bf(p1));
            t.y = pk2(f2bf(p2), f2bf(p3));
            *(uint2*)((char*)QPs + swz16(w * 16 + lr, nf * 32 + lg * 8)) = t;
        }

        // O += P @ V (wave-local P rows)
        #pragma unroll
        for (int ks = 0; ks < 2; ++ks) {
            bf16x8 pa = *(const bf16x8*)((char*)QPs + swz16(w * 16 + lr, ks * 64 + lg * 16));
            #pragma unroll
            for (int d = 0; d < 4; ++d) {
                bf16x8 vb = *(const bf16x8*)((char*)Vs + swz16(d * 16 + lr, ks * 64 + lg * 16));
                po[d] = MFMA16(pa, vb, po[d]);
            }
        }

        __syncthreads();               // all Ks/Vs reads done
        if (kt < 16) writeKV();        // overwrite with next tile
        __syncthreads();               // writes visible
    }

    // final denominator reduce (across lg groups) + redistribute to po rows
    lsum += __shfl_xor(lsum, 16, 64);
    lsum += __shfl_xor(lsum, 32, 64);
    #pragma unroll
    for (int e = 0; e < 4; ++e) {
        float le = __shfl(lsum, lg * 4 + e, 16);   // l for q-row lg*4+e of this wave
        int qr = q0 + w * 16 + lg * 4 + e;
        if (qr <= 1024) {
            float inv = 1.0f / le;
            #pragma unroll
            for (int d = 0; d < 4; ++d)
                Ctx[(rowbase + qr) * 256 + h * 64 + d * 16 + lr] = f2bf(po[d][e] * inv);
        }
    }
}

// ---------------- classifier head (bf16 cls rows) ----------------
__global__ void head_kernel(const ushort* __restrict__ ybf,
                            const float* __restrict__ hw,
                            const float* __restrict__ hb,
                            float* __restrict__ out)
{
    int i = blockIdx.x * 256 + threadIdx.x;
    if (i >= BATCH * NCLS) return;
    int b = i / NCLS, c = i % NCLS;
    const ushort* xr = ybf + (size_t)b * NTOK * DMODEL;   // cls row of batch b
    float acc = hb[c];
    for (int t = 0; t < DMODEL; ++t) acc += bf2f(xr[t]) * hw[t * NCLS + c];
    out[i] = acc;
}

// ---------------- launch ----------------
extern "C" void kernel_launch(void* const* d_in, const int* in_sizes, int n_in,
                              void* d_out, int out_size, void* d_ws, size_t ws_size,
                              hipStream_t stream) {
    const float* x      = (const float*)d_in[0];
    const float* conv_w = (const float*)d_in[1];
    const float* conv_b = (const float*)d_in[2];
    const float* cls_tok= (const float*)d_in[3];
    const float* ln1_g  = (const float*)d_in[4];
    const float* ln1_b  = (const float*)d_in[5];
    const float* wq     = (const float*)d_in[6];
    const float* bq     = (const float*)d_in[7];
    const float* wk     = (const float*)d_in[8];
    const float* bk     = (const float*)d_in[9];
    const float* wv     = (const float*)d_in[10];
    const float* bv     = (const float*)d_in[11];
    const float* wo     = (const float*)d_in[12];
    const float* bo     = (const float*)d_in[13];
    const float* ln2_g  = (const float*)d_in[14];
    const float* ln2_b  = (const float*)d_in[15];
    const float* w1     = (const float*)d_in[16];
    const float* b1     = (const float*)d_in[17];
    const float* w2     = (const float*)d_in[18];
    const float* b2     = (const float*)d_in[19];
    const float* lnf_g  = (const float*)d_in[20];
    const float* lnf_b  = (const float*)d_in[21];
    const float* head_w = (const float*)d_in[22];
    const float* head_b = (const float*)d_in[23];

    char* p = (char*)d_ws;
    float* h    = (float*)p;            p += (size_t)NROWS * DMODEL * 4;
    float* cosb = (float*)p;            p += (size_t)NTOK * 128 * 4;
    float* sinb = (float*)p;            p += (size_t)NTOK * 128 * 4;
    ushort* ybf = (ushort*)p;           p += (size_t)NROWS * DMODEL * 2;
    ushort* cbf = (ushort*)p;           p += (size_t)NROWS * DMODEL * 2;
    ushort* qbf = (ushort*)p;           p += (size_t)NROWS * DMODEL * 2;
    ushort* kbf = (ushort*)p;           p += (size_t)NROWS * DMODEL * 2;
    ushort* vT  = (ushort*)p;           p += (size_t)BATCH * 256 * VSTR * 2 + 256;
    ushort* hidbf = (ushort*)p;         p += (size_t)NROWS * HIDDEN * 2;
    ushort* wqkvT = (ushort*)p;         p += (size_t)LAYERS * 768 * DMODEL * 2;
    ushort* woT = (ushort*)p;           p += (size_t)LAYERS * DMODEL * DMODEL * 2;
    ushort* w1T = (ushort*)p;           p += (size_t)LAYERS * DMODEL * HIDDEN * 2;
    ushort* w2T = (ushort*)p;           p += (size_t)LAYERS * DMODEL * HIDDEN * 2;
    ushort* cwb = (ushort*)p;           p += (size_t)DMODEL * 768 * 2;

    // one-time prep (deterministic, every call) — separate kernels (merged variant crashes)
    transpose_cvt_kernel<<<dim3(8, 8, LAYERS), 256, 0, stream>>>(
        wq, wqkvT, 256, 256, 65536, 196608);
    transpose_cvt_kernel<<<dim3(8, 8, LAYERS), 256, 0, stream>>>(
        wk, wqkvT + 65536, 256, 256, 65536, 196608);
    transpose_cvt_kernel<<<dim3(8, 8, LAYERS), 256, 0, stream>>>(
        wv, wqkvT + 131072, 256, 256, 65536, 196608);
    transpose_cvt_kernel<<<dim3(8, 8, LAYERS), 256, 0, stream>>>(
        wo, woT, 256, 256, 65536, 65536);
    transpose_cvt_kernel<<<dim3(32, 8, LAYERS), 256, 0, stream>>>(
        w1, w1T, 256, 1024, 262144, 262144);
    transpose_cvt_kernel<<<dim3(8, 32, LAYERS), 256, 0, stream>>>(
        w2, w2T, 1024, 256, 262144, 262144);
    rope_tab_kernel<<<(NTOK * 128 + 255) / 256, 256, 0, stream>>>(cosb, sinb);
    cls_kernel<<<BATCH, 256, 0, stream>>>(cls_tok, h);
    cvt_bf16_kernel<<<192, 256, 0, stream>>>(conv_w, cwb, DMODEL * 768);
    patch_gemm<<<512, 256, 0, stream>>>(x, cwb, conv_b, h);

    const int M = NROWS;
    int grln = (M + 63) / 64;

    // layer-0 LN1
    ln_kernel<<<(M + 3) / 4, 256, 0, stream>>>(h, ybf, ln1_g, ln1_b, M);

    for (int l = 0; l < LAYERS; ++l) {
        const ushort* WqkvT = wqkvT + (size_t)l * 768 * DMODEL;
        const ushort* WoT = woT + (size_t)l * DMODEL * DMODEL;
        const ushort* W1T = w1T + (size_t)l * DMODEL * HIDDEN;
        const ushort* W2T = w2T + (size_t)l * DMODEL * HIDDEN;

        gemm_qkv<<<816, 512, 0, stream>>>(ybf, WqkvT, bq + l * DMODEL, bk + l * DMODEL,
                                          bv + l * DMODEL, qbf, kbf, vT, cosb, sinb, M);
        flash_mfma<<<1088, 256, 0, stream>>>(qbf, kbf, vT, cbf);
        // h += ctx@Wo + bo ; ybf = LN2(h)
        gemm_res_ln<<<grln, 512, 0, stream>>>(cbf, WoT, bo + l * DMODEL, h, ybf,
                                              ln2_g + l * DMODEL, ln2_b + l * DMODEL,
                                              M, DMODEL);
        gemm_gelu<<<1088, 512, 0, stream>>>(ybf, W1T, b1 + l * HIDDEN, hidbf, M);
        // h += hid@W2 + b2 ; ybf = LN1_{l+1}(h)  (last layer: LNf)
        const float* ng = (l < LAYERS - 1) ? ln1_g + (l + 1) * DMODEL : lnf_g;
        const float* nb = (l < LAYERS - 1) ? ln1_b + (l + 1) * DMODEL : lnf_b;
        gemm_res_ln<<<grln, 512, 0, stream>>>(hidbf, W2T, b2 + l * DMODEL, h, ybf,
                                              ng, nb, M, HIDDEN);
    }
    head_kernel<<<(BATCH * NCLS + 255) / 256, 256, 0, stream>>>(ybf, head_w, head_b,
                                                                (float*)d_out);
}